// Round 6
// baseline (9068.584 us; speedup 1.0000x reference)
//
#include <hip/hip_runtime.h>
#include <hip/hip_bf16.h>
#include <math.h>

// LSTM decoder: B=64, T=512, IN=256, OUT=256, H=1024, 2 layers + linear head.
// Round 10: anti-DVFS. Counter arithmetic (MfmaUtil 4.1% vs ~480 busy
// MFMA cy/SIMD/step over 17.3us steps) implies an effective clock of
// ~675 MHz, not 2400 — the governor sees a 95%-idle chip (s_barrier +
// s_sleep everywhere) and drops the DPM state. Every latency model that
// "missed" 12us/step was off by exactly this clock ratio.
// Changes vs R9 (structure otherwise identical):
//  - No s_sleep anywhere; all polls use short independent-FMA backoff.
//  - During the release wait, waves 1..7 spin on an LDS mailbox (s_go,
//    set by wave 0 after detect + inv; buffer_inv is per-CU so one wave
//    covers the block) running continuous v_fmac chains -> VALU stays
//    busy, no LLC traffic, clocks stay up.
//  - x-prefetch dropped (its L2 lines were invalidated by the aggregator
//    fence before use — dead work in the R9 ordering).

typedef __attribute__((ext_vector_type(8))) short bf16x8;   // 8 x bf16
typedef __attribute__((ext_vector_type(4))) float f32x4;
typedef unsigned long long u64;

__device__ __forceinline__ float sigm(float v) {
  return 1.f / (1.f + __expf(-v));
}
__device__ __forceinline__ float ftanh(float v) {
  return 2.f / (1.f + __expf(-2.f * v)) - 1.f;
}

__device__ __forceinline__ unsigned short bf16_bits(float v) {
  __hip_bfloat16 hb = __float2bfloat16(v);
  unsigned short us;
  __builtin_memcpy(&us, &hb, 2);
  return us;
}

// write-through (sc0 sc1) 2B store
__device__ __forceinline__ void vstore_bf16(__hip_bfloat16* p, float v) {
  *(volatile unsigned short*)p = bf16_bits(v);
}

// independent-FMA busy loop: keeps the SIMD issuing (anti-DVFS), never
// optimized away, no memory traffic.
__device__ __forceinline__ void busy_fma(int iters) {
  float c0 = 1.1f, c1 = 1.2f, c2 = 1.3f, c3 = 1.4f;
  const float a = 1.0000001f, b = 0.9999999f;
  for (int i = 0; i < iters; ++i) {
    asm volatile(
        "v_fmac_f32 %0, %4, %5\n"
        "v_fmac_f32 %1, %4, %5\n"
        "v_fmac_f32 %2, %4, %5\n"
        "v_fmac_f32 %3, %4, %5\n"
        : "+v"(c0), "+v"(c1), "+v"(c2), "+v"(c3)
        : "v"(a), "v"(b));
  }
  asm volatile("" ::"v"(c0), "v"(c1), "v"(c2), "v"(c3));
}

// ---------------- prep kernels (one-time per launch) ----------------

// W0cat[u*4+g][k] : k<256 -> Wih0[g*1024+u][k], else Whh0[g*1024+u][k-256]
__global__ __launch_bounds__(256) void prep_w0(const float* __restrict__ Wih0,
                                               const float* __restrict__ Whh0,
                                               __hip_bfloat16* __restrict__ W0) {
  const unsigned n = 4096u * 1280u;
  for (unsigned d = blockIdx.x * blockDim.x + threadIdx.x; d < n;
       d += blockDim.x * gridDim.x) {
    unsigned r = d / 1280u;
    unsigned k = d - r * 1280u;
    unsigned u = r >> 2, g = r & 3u;
    unsigned srow = g * 1024u + u;
    float v = (k < 256u) ? Wih0[(size_t)srow * 256u + k]
                         : Whh0[(size_t)srow * 1024u + (k - 256u)];
    W0[d] = __float2bfloat16(v);
  }
}

// W1ext[4352][2048]: rows<4096 reordered LSTM1 weights [Wih1|Whh1];
// rows 4096+o: [zeros(1024) | Wlin[o]]
__global__ __launch_bounds__(256) void prep_w1(const float* __restrict__ Wih1,
                                               const float* __restrict__ Whh1,
                                               const float* __restrict__ Wlin,
                                               __hip_bfloat16* __restrict__ W1) {
  const unsigned n = 4352u * 2048u;
  for (unsigned d = blockIdx.x * blockDim.x + threadIdx.x; d < n;
       d += blockDim.x * gridDim.x) {
    unsigned r = d >> 11;
    unsigned k = d & 2047u;
    float v;
    if (r < 4096u) {
      unsigned u = r >> 2, g = r & 3u;
      unsigned srow = g * 1024u + u;
      v = (k < 1024u) ? Wih1[(size_t)srow * 1024u + k]
                      : Whh1[(size_t)srow * 1024u + (k - 1024u)];
    } else {
      unsigned o = r - 4096u;
      v = (k < 1024u) ? 0.f : Wlin[(size_t)o * 1024u + (k - 1024u)];
    }
    W1[d] = __float2bfloat16(v);
  }
}

// xbf[t][b][k] = bf16( t==0 ? 0 : x[b][t-1][k] )   (teacher forcing shift)
__global__ __launch_bounds__(256) void prep_x(const float* __restrict__ x,
                                              __hip_bfloat16* __restrict__ xbf) {
  const unsigned n = 512u * 64u * 256u;
  for (unsigned d = blockIdx.x * blockDim.x + threadIdx.x; d < n;
       d += blockDim.x * gridDim.x) {
    unsigned t = d >> 14;
    unsigned b = (d >> 8) & 63u;
    unsigned k = d & 255u;
    float v = (t == 0u) ? 0.f : x[((size_t)b * 512u + (t - 1u)) * 256u + k];
    xbf[d] = __float2bfloat16(v);
  }
}

// biases (gate-interleaved, bih+bhh combined) + h init: h0[-1] -> slot 0,
// h1[-1] -> slot 2 (h1[tau] lives in slot tau%3; tau=-1 -> 2)
__global__ __launch_bounds__(256) void prep_misc(
    const float* __restrict__ bih0, const float* __restrict__ bhh0,
    const float* __restrict__ bih1, const float* __restrict__ bhh1,
    const float* __restrict__ z, float* __restrict__ b0, float* __restrict__ b1,
    __hip_bfloat16* __restrict__ h0buf, __hip_bfloat16* __restrict__ h1buf) {
  for (int i = blockIdx.x * blockDim.x + threadIdx.x; i < 73728;
       i += blockDim.x * gridDim.x) {
    if (i < 4096) {
      int u = i >> 2, g = i & 3;
      b0[i] = bih0[g * 1024 + u] + bhh0[g * 1024 + u];
    } else if (i < 8192) {
      int r = i - 4096;
      int u = r >> 2, g = r & 3;
      b1[r] = bih1[g * 1024 + u] + bhh1[g * 1024 + u];
    } else {
      int j = i - 8192;  // 0..65535
      float zv = z[j];
      vstore_bf16(h0buf + j, zv);                       // h0 slot 0
      vstore_bf16(h1buf + 2 * 65536 + j, zv);           // h1 slot 2
    }
  }
}

// ---------------- projection helper (blocks 64..127) ----------------
// out[pbat*16 .. +16, t_out, pcol*16 .. +16) = h1p @ Wlin^T + blin

__device__ __forceinline__ void do_proj(const __hip_bfloat16* __restrict__ h1p,
                                        const bf16x8* wp, float (*red)[16][68],
                                        const float* __restrict__ blin,
                                        float* __restrict__ out, int pcol,
                                        int pbat, int t_out, int tid, int w,
                                        int col, int kq) {
  f32x4 a0 = {0.f, 0.f, 0.f, 0.f};
  const __hip_bfloat16* ab =
      h1p + ((size_t)((pbat << 4) + col) << 10) + (w << 7) + (kq << 3);
#pragma unroll
  for (int c = 0; c < 4; ++c) {
    bf16x8 f = *(const bf16x8*)(ab + (c << 5));
    a0 = __builtin_amdgcn_mfma_f32_16x16x32_bf16(f, wp[c], a0, 0, 0, 0);
  }
  *(f32x4*)&red[w][col][(kq << 2)] = a0;
  __syncthreads();
  if (tid < 256) {
    int o_l = tid & 15, b = tid >> 4;  // b: 0..15
    float v = blin[(pcol << 4) + o_l];
#pragma unroll
    for (int ww = 0; ww < 8; ++ww) v += red[ww][o_l][b];
    out[(((size_t)((pbat << 4) + b) << 9) + (size_t)t_out) * 256 + (pcol << 4) +
        o_l] = v;
  }
  // no trailing sync: every call site is followed by a block-wide barrier
  // before red is written again.
}

// ---------------- persistent kernel ----------------

__global__ __launch_bounds__(512) void k_persist(
    const __hip_bfloat16* __restrict__ xbf, const __hip_bfloat16* __restrict__ W0,
    const __hip_bfloat16* __restrict__ W1, const float* __restrict__ b0,
    const float* __restrict__ b1, const float* __restrict__ blin,
    __hip_bfloat16* __restrict__ h0buf, __hip_bfloat16* __restrict__ h1buf,
    float* __restrict__ out, unsigned* __restrict__ flags) {
  const int tid = threadIdx.x;
  const int lane = tid & 63;
  const int w = tid >> 6;          // wave id = K-split index (0..7)
  const int bid = blockIdx.x;
  const int cb = bid << 4;         // 16 gate-columns owned by this block
  const int col = lane & 15;
  const int kq = lane >> 4;
  const int n = cb + col;
  const bool isproj = (bid >= 64 && bid < 128);
  const int pcol = bid & 15;       // proj: out-col tile
  const int pbat = (bid >> 4) & 3; // proj: batch tile

  // ---- per-XCD aggregator election ----
  // flags layout (words): [0..255] flags; [256..263] lead; [272+16x] release.
  __shared__ int s_agg, s_xcd;
  __shared__ unsigned s_go;  // LDS mailbox: release broadcast within block
  {
    unsigned* lead = flags + 256;
    if (tid == 0) {
      unsigned xcc = 0;
      asm volatile("s_getreg_b32 %0, hwreg(HW_REG_XCC_ID)" : "=s"(xcc));
      xcc &= 7u;
      unsigned old = __hip_atomic_fetch_add(&lead[xcc], 1u, __ATOMIC_RELAXED,
                                            __HIP_MEMORY_SCOPE_AGENT);
      s_agg = (old == 0u) ? 1 : 0;
      s_xcd = (int)xcc;
      s_go = 0u;
    }
  }

  // ---- weights -> registers (persist across all 512 steps) ----
  bf16x8 wa[5], wb[8], wp[4];
  {
    const __hip_bfloat16* p = W0 + (size_t)n * 1280 + w * 160 + (kq << 3);
#pragma unroll
    for (int c = 0; c < 5; ++c) wa[c] = *(const bf16x8*)(p + (c << 5));
  }
  {
    const __hip_bfloat16* p = W1 + ((size_t)n << 11) + (w << 8) + (kq << 3);
#pragma unroll
    for (int c = 0; c < 8; ++c) wb[c] = *(const bf16x8*)(p + (c << 5));
  }
  if (isproj) {
    const __hip_bfloat16* p = W1 +
        ((size_t)(4096 + (pcol << 4) + col) << 11) + 1024 + (w << 7) + (kq << 3);
#pragma unroll
    for (int c = 0; c < 4; ++c) wp[c] = *(const bf16x8*)(p + (c << 5));
  }

  // cell threads: tid<256 own (unit u_l of 4, batch bq); c-state in registers
  const int u_l = tid & 3, bq = tid >> 2;
  float bias0[4], bias1[4];
  if (tid < 256) {
#pragma unroll
    for (int g = 0; g < 4; ++g) {
      bias0[g] = b0[cb + (u_l << 2) + g];
      bias1[g] = b1[cb + (u_l << 2) + g];
    }
  }
  float c0v = 0.f, c1v = 0.f;

  __shared__ float red[8][16][68];  // K-partials; 68 keeps 16B alignment

  __syncthreads();  // s_agg/s_xcd/s_go visible to all waves

  unsigned* rel = flags + 272 + (s_xcd << 4);  // this XCD's release word

  for (int t = 0; t < 512; ++t) {
    const __hip_bfloat16* h0prev = h0buf + ((size_t)(t & 1) << 16);
    const __hip_bfloat16* h0cur = h0buf + ((size_t)((t + 1) & 1) << 16);
    const __hip_bfloat16* h1prev = h1buf + ((size_t)((t + 2) % 3) << 16);

    // ======== phase A: gates0 = [x_t | h0prev] @ W0cat^T ========
    {
      f32x4 a0 = {0.f, 0.f, 0.f, 0.f}, a1 = a0, a2 = a0, a3 = a0;
#pragma unroll
      for (int c = 0; c < 5; ++c) {
        const int k0 = w * 160 + (c << 5);
        const __hip_bfloat16* ab;
        size_t rs;
        if (k0 < 256) {  // x part
          ab = xbf + ((size_t)t << 14) + k0 + (kq << 3);
          rs = 256;
        } else {         // h part
          ab = h0prev + (k0 - 256) + (kq << 3);
          rs = 1024;
        }
        bf16x8 f0 = *(const bf16x8*)(ab + (size_t)col * rs);
        bf16x8 f1 = *(const bf16x8*)(ab + (size_t)(16 + col) * rs);
        bf16x8 f2 = *(const bf16x8*)(ab + (size_t)(32 + col) * rs);
        bf16x8 f3 = *(const bf16x8*)(ab + (size_t)(48 + col) * rs);
        a0 = __builtin_amdgcn_mfma_f32_16x16x32_bf16(f0, wa[c], a0, 0, 0, 0);
        a1 = __builtin_amdgcn_mfma_f32_16x16x32_bf16(f1, wa[c], a1, 0, 0, 0);
        a2 = __builtin_amdgcn_mfma_f32_16x16x32_bf16(f2, wa[c], a2, 0, 0, 0);
        a3 = __builtin_amdgcn_mfma_f32_16x16x32_bf16(f3, wa[c], a3, 0, 0, 0);
      }
      *(f32x4*)&red[w][col][(kq << 2)] = a0;
      *(f32x4*)&red[w][col][16 + (kq << 2)] = a1;
      *(f32x4*)&red[w][col][32 + (kq << 2)] = a2;
      *(f32x4*)&red[w][col][48 + (kq << 2)] = a3;
    }
    __syncthreads();
    if (tid < 256) {  // 8-way K-reduce + LSTM cell 0 -> direct 2B publish
      float gg[4];
#pragma unroll
      for (int g = 0; g < 4; ++g) {
        float v = bias0[g];
#pragma unroll
        for (int ww = 0; ww < 8; ++ww) v += red[ww][(u_l << 2) + g][bq];
        gg[g] = v;
      }
      float cn = sigm(gg[1]) * c0v + sigm(gg[0]) * ftanh(gg[2]);
      c0v = cn;
      vstore_bf16((__hip_bfloat16*)h0cur + ((size_t)bq << 10) + (cb >> 2) + u_l,
                  sigm(gg[3]) * ftanh(cn));
    }
    __syncthreads();  // red free; publish stores issued

    // ---- window work: proj out[t-2] (blocks 64..127) ----
    if (isproj && t >= 2) {
      do_proj(h1buf + (((size_t)((t + 1) % 3)) << 16), wp, red, blin, out,
              pcol, pbat, t - 2, tid, w, col, kq);
    }

    // ---- drain + arrive + hierarchical release (busy, never idle) ----
    __builtin_amdgcn_s_waitcnt(0);  // per-wave: publishes / proj-outs drained
    __syncthreads();                // all waves drained before the flag
    if (tid == 0)
      __hip_atomic_store(&flags[bid], (unsigned)(t + 1), __ATOMIC_RELAXED,
                         __HIP_MEMORY_SCOPE_AGENT);
    const unsigned tgt = (unsigned)(t + 1);
    if (w == 0) {
      if (s_agg) {
        // aggregator: the ONLY all-256 poller on this XCD
        const u64* fq = (const u64*)flags;
        for (;;) {
          u64 q0 = __hip_atomic_load(&fq[2 * lane], __ATOMIC_RELAXED,
                                     __HIP_MEMORY_SCOPE_AGENT);
          u64 q1 = __hip_atomic_load(&fq[2 * lane + 1], __ATOMIC_RELAXED,
                                     __HIP_MEMORY_SCOPE_AGENT);
          int ok = ((unsigned)q0 >= tgt) & ((unsigned)(q0 >> 32) >= tgt) &
                   ((unsigned)q1 >= tgt) & ((unsigned)(q1 >> 32) >= tgt);
          if (__all(ok)) break;
          busy_fma(4);
        }
        // per-XCD leader fence: waitcnt + L1/L2 inv (proven codegen)
        __builtin_amdgcn_fence(__ATOMIC_ACQUIRE, "agent");
        if (lane == 0)
          __hip_atomic_store(rel, tgt, __ATOMIC_RELAXED,
                             __HIP_MEMORY_SCOPE_AGENT);
      } else {
        // follower w0: poll ONE word (this XCD's release line)
        while (__hip_atomic_load(rel, __ATOMIC_RELAXED,
                                 __HIP_MEMORY_SCOPE_AGENT) < tgt)
          busy_fma(4);
        if (bid < 8) {
          // belt: full fence in case XCC_ID lies about topology
          __builtin_amdgcn_fence(__ATOMIC_ACQUIRE, "agent");
        } else {
          __builtin_amdgcn_sched_barrier(0);
          asm volatile("buffer_inv" ::: "memory");  // L1-only inv (per-CU op)
          __builtin_amdgcn_sched_barrier(0);
        }
      }
      // broadcast within the block: waves 1..7 are FMA-spinning on s_go
      __builtin_amdgcn_sched_barrier(0);
      if (lane == 0) *(volatile unsigned*)&s_go = tgt;
    } else {
      // waves 1..7: busy-spin on the LDS mailbox (keeps SIMDs issuing ->
      // DVFS governor sees an active chip; no LLC traffic)
      while (*(volatile unsigned*)&s_go < tgt) busy_fma(8);
    }
    __syncthreads();

    // ======== phase B: gates1 = [h0cur | h1prev] @ W1^T ========
    {
      const __hip_bfloat16* ab =
          ((w < 4) ? h0cur : h1prev) + ((w & 3) << 8) + (kq << 3);
      f32x4 a0 = {0.f, 0.f, 0.f, 0.f}, a1 = a0, a2 = a0, a3 = a0;
#pragma unroll
      for (int c = 0; c < 8; ++c) {
        const __hip_bfloat16* p = ab + (c << 5);
        bf16x8 f0 = *(const bf16x8*)(p + ((size_t)col << 10));
        bf16x8 f1 = *(const bf16x8*)(p + ((size_t)(16 + col) << 10));
        bf16x8 f2 = *(const bf16x8*)(p + ((size_t)(32 + col) << 10));
        bf16x8 f3 = *(const bf16x8*)(p + ((size_t)(48 + col) << 10));
        a0 = __builtin_amdgcn_mfma_f32_16x16x32_bf16(f0, wb[c], a0, 0, 0, 0);
        a1 = __builtin_amdgcn_mfma_f32_16x16x32_bf16(f1, wb[c], a1, 0, 0, 0);
        a2 = __builtin_amdgcn_mfma_f32_16x16x32_bf16(f2, wb[c], a2, 0, 0, 0);
        a3 = __builtin_amdgcn_mfma_f32_16x16x32_bf16(f3, wb[c], a3, 0, 0, 0);
      }
      *(f32x4*)&red[w][col][(kq << 2)] = a0;
      *(f32x4*)&red[w][col][16 + (kq << 2)] = a1;
      *(f32x4*)&red[w][col][32 + (kq << 2)] = a2;
      *(f32x4*)&red[w][col][48 + (kq << 2)] = a3;
    }
    __syncthreads();
    if (tid < 256) {  // 8-way K-reduce + LSTM cell 1 -> direct 2B publish
      float gg[4];
#pragma unroll
      for (int g = 0; g < 4; ++g) {
        float v = bias1[g];
#pragma unroll
        for (int ww = 0; ww < 8; ++ww) v += red[ww][(u_l << 2) + g][bq];
        gg[g] = v;
      }
      float cn = sigm(gg[1]) * c1v + sigm(gg[0]) * ftanh(gg[2]);
      c1v = cn;
      // h1[t] -> slot t%3 (drains at next step's pre-flag waitcnt)
      vstore_bf16(h1buf + ((size_t)(t % 3) << 16) + ((size_t)bq << 10) +
                      (cb >> 2) + u_l,
                  sigm(gg[3]) * ftanh(cn));
    }
    __syncthreads();  // red safe for next iteration's phase A
  }

  // ---- tail: h1[510] in slot 0, h1[511] in slot 1 (just published) ----
  __builtin_amdgcn_s_waitcnt(0);  // per-wave drain of h1[511] publishes
  __syncthreads();
  if (tid == 0)
    __hip_atomic_store(&flags[bid], 513u, __ATOMIC_RELAXED,
                       __HIP_MEMORY_SCOPE_AGENT);
  if (w == 0 && s_agg) {
    const u64* fq = (const u64*)flags;
    for (;;) {
      u64 q0 = __hip_atomic_load(&fq[2 * lane], __ATOMIC_RELAXED,
                                 __HIP_MEMORY_SCOPE_AGENT);
      u64 q1 = __hip_atomic_load(&fq[2 * lane + 1], __ATOMIC_RELAXED,
                                 __HIP_MEMORY_SCOPE_AGENT);
      int ok = ((unsigned)q0 >= 513u) & ((unsigned)(q0 >> 32) >= 513u) &
               ((unsigned)q1 >= 513u) & ((unsigned)(q1 >> 32) >= 513u);
      if (__all(ok)) break;
      busy_fma(4);
    }
    __builtin_amdgcn_fence(__ATOMIC_ACQUIRE, "agent");
    if (lane == 0)
      __hip_atomic_store(rel, 513u, __ATOMIC_RELAXED,
                         __HIP_MEMORY_SCOPE_AGENT);
  }
  if (!isproj) return;
  if (w == 0) {
    if (!s_agg) {
      while (__hip_atomic_load(rel, __ATOMIC_RELAXED,
                               __HIP_MEMORY_SCOPE_AGENT) < 513u)
        busy_fma(4);
      // one-time full acquire before reading h1[510]/h1[511]
      __builtin_amdgcn_fence(__ATOMIC_ACQUIRE, "agent");
    }
    __builtin_amdgcn_sched_barrier(0);
    if (lane == 0) *(volatile unsigned*)&s_go = 513u;
  } else {
    while (*(volatile unsigned*)&s_go < 513u) busy_fma(8);
  }
  __syncthreads();
  do_proj(h1buf, wp, red, blin, out, pcol, pbat, 510, tid, w, col, kq);
  __syncthreads();  // red reuse barrier between the two tail projections
  do_proj(h1buf + ((size_t)1 << 16), wp, red, blin, out, pcol, pbat, 511, tid,
          w, col, kq);
}

// ---------------- host launch ----------------

extern "C" void kernel_launch(void* const* d_in, const int* in_sizes, int n_in,
                              void* d_out, int out_size, void* d_ws, size_t ws_size,
                              hipStream_t stream) {
  const float* z = (const float*)d_in[0];
  const float* x = (const float*)d_in[1];
  const float* Wih0 = (const float*)d_in[2];
  const float* Whh0 = (const float*)d_in[3];
  const float* bih0 = (const float*)d_in[4];
  const float* bhh0 = (const float*)d_in[5];
  const float* Wih1 = (const float*)d_in[6];
  const float* Whh1 = (const float*)d_in[7];
  const float* bih1 = (const float*)d_in[8];
  const float* bhh1 = (const float*)d_in[9];
  const float* Wlin = (const float*)d_in[10];
  const float* blin = (const float*)d_in[11];
  float* out = (float*)d_out;

  char* ws = (char*)d_ws;
  __hip_bfloat16* W0 = (__hip_bfloat16*)(ws);                // 10,485,760 B
  __hip_bfloat16* W1 = (__hip_bfloat16*)(ws + 10485760);     // 17,825,792 B
  __hip_bfloat16* xbf = (__hip_bfloat16*)(ws + 28311552);    // 16,777,216 B
  float* b0 = (float*)(ws + 45088768);                       // 16,384 B
  float* b1 = (float*)(ws + 45105152);                       // 16,384 B
  __hip_bfloat16* h0buf = (__hip_bfloat16*)(ws + 45121536);  // 262,144 B (2 slots)
  __hip_bfloat16* h1buf = (__hip_bfloat16*)(ws + 45383680);  // 393,216 B (3 slots)
  unsigned* flags = (unsigned*)(ws + 45776896);              // 4,096 B

  hipMemsetAsync(flags, 0, 4096, stream);  // ws is re-poisoned every call
  prep_w0<<<4096, 256, 0, stream>>>(Wih0, Whh0, W0);
  prep_w1<<<4096, 256, 0, stream>>>(Wih1, Whh1, Wlin, W1);
  prep_x<<<4096, 256, 0, stream>>>(x, xbf);
  prep_misc<<<288, 256, 0, stream>>>(bih0, bhh0, bih1, bhh1, z, b0, b1, h0buf,
                                     h1buf);

  k_persist<<<256, 512, 0, stream>>>(xbf, W0, W1, b0, b1, blin, h0buf, h1buf,
                                     out, flags);
}